// Round 6
// baseline (683.221 us; speedup 1.0000x reference)
//
#include <hip/hip_runtime.h>

typedef unsigned long long u64;

// Pass-through that makes the value asm-defined: the compiler cannot
// rematerialize the originating load inside the loop.
__device__ __forceinline__ u64 opaque64(u64 x) { asm volatile("" : "+v"(x)); return x; }

// Workgroup barrier that orders LDS only (no vmcnt drain), so global-memory
// prefetch loads stay in flight across it.
__device__ __forceinline__ void lds_barrier() {
    asm volatile("s_waitcnt lgkmcnt(0)" ::: "memory");
    __builtin_amdgcn_s_barrier();
    asm volatile("" ::: "memory");
}

// ---------------- amax over |emb| ----------------
__global__ void amax_kernel(const float* __restrict__ emb, unsigned int* __restrict__ out) {
    const int n4 = (32000 * 256) / 4;
    float m = 0.0f;
    const float4* e4 = (const float4*)emb;
    for (int i = blockIdx.x * blockDim.x + threadIdx.x; i < n4; i += gridDim.x * blockDim.x) {
        float4 v = e4[i];
        m = fmaxf(m, fmaxf(fmaxf(fabsf(v.x), fabsf(v.y)), fmaxf(fabsf(v.z), fabsf(v.w))));
    }
#pragma unroll
    for (int off = 32; off > 0; off >>= 1) m = fmaxf(m, __shfl_down(m, off, 64));
    if ((threadIdx.x & 63) == 0) atomicMax(out, __float_as_uint(m));
}

// ---------------- weight bit packing (weights only now) ----------------
// One wave packs 16 words (1024 consecutive floats). Section boundaries
// {2048,6144,10240,14336} are multiples of 16; Wfc is the 8-word tail.
__global__ void pack_kernel(const float* __restrict__ Wih0, const float* __restrict__ Whh0,
                            const float* __restrict__ Wih1, const float* __restrict__ Whh1,
                            const float* __restrict__ Wfc,
                            u64* __restrict__ w0b, u64* __restrict__ u0b,
                            u64* __restrict__ w1b, u64* __restrict__ u1b, u64* __restrict__ wfcb) {
    const int gw = (blockIdx.x * blockDim.x + threadIdx.x) >> 6;  // global wave id
    const int lane = threadIdx.x & 63;
    if (gw >= 897) return;
    const int wb = gw * 16;  // first packed word of this chunk

    const float* srcb; u64* dstb; int nw = 16;
    if (wb < 2048)       { srcb = Wih0 + (long long)wb * 64;           dstb = w0b + wb; }
    else if (wb < 6144)  { srcb = Whh0 + (long long)(wb - 2048) * 64;  dstb = u0b + (wb - 2048); }
    else if (wb < 10240) { srcb = Wih1 + (long long)(wb - 6144) * 64;  dstb = w1b + (wb - 6144); }
    else if (wb < 14336) { srcb = Whh1 + (long long)(wb - 10240) * 64; dstb = u1b + (wb - 10240); }
    else                 { srcb = Wfc  + (long long)(wb - 14336) * 64; dstb = wfcb + (wb - 14336); nw = 8; }

    u64 mine = 0;
    for (int k0 = 0; k0 < nw; k0 += 8) {
        float v[8];
#pragma unroll
        for (int j = 0; j < 8; ++j) v[j] = srcb[(long long)(k0 + j) * 64 + lane];
#pragma unroll
        for (int j = 0; j < 8; ++j) {
            u64 bits = __ballot(v[j] >= 0.0f);
            if (lane == k0 + j) mine = bits;
        }
    }
    if (lane < nw) dstb[lane] = mine;   // coalesced 8B stores
}

// ---------------- layer-0 input-threshold precompute ----------------
// Binarizes its 8 emb rows inline (bit = v >= -s/2  <=>  rint(v/s) >= 0 for
// power-of-two s), then T0 = floor((512+xw)/2), xw = fl(fl((256-2*mm)+bih0)+bhh0).
// Exact: sign(fl(xw + (512-2*mh0))) >= 0 <=> mh0 <= T0.  Stored as i16 pairs:
// dword (b*256 + t/2)*512 + h holds {t even, t odd}.
__global__ void xw_kernel(const int* __restrict__ text,
                          const float* __restrict__ bih0, const float* __restrict__ bhh0,
                          const float* __restrict__ emb, const unsigned int* __restrict__ amax_bits,
                          const u64* __restrict__ w0b, int* __restrict__ T0p) {
    const int tid = threadIdx.x;
    const int lane = tid & 63;
    const int wv = tid >> 6;
    const int b = blockIdx.x >> 6;
    const int tg = blockIdx.x & 63;   // covers t = tg*8 .. tg*8+7
    __shared__ int toks[8];
    __shared__ u64 xbs[8][4];
    if (tid < 8) toks[tid] = text[b * 512 + tg * 8 + tid];
    u64 w0[4];
#pragma unroll
    for (int w = 0; w < 4; ++w) w0[w] = w0b[tid * 4 + w];
    const float bi = bih0[tid], bh = bhh0[tid];
    float amax = __uint_as_float(*amax_bits) + 1e-12f;
    float s = exp2f(ceilf(log2f(amax / 127.0f)));   // power of two
    float thr = -0.5f * s;
    __syncthreads();   // toks visible
    {   // wave wv binarizes row of token toks[wv]: coalesced 256B reads + ballots
        const float* row = emb + (size_t)toks[wv] * 256;
        float v0 = row[lane], v1 = row[64 + lane], v2 = row[128 + lane], v3 = row[192 + lane];
        u64 b0 = __ballot(v0 >= thr);
        u64 b1 = __ballot(v1 >= thr);
        u64 b2 = __ballot(v2 >= thr);
        u64 b3 = __ballot(v3 >= thr);
        if (lane == 0) { xbs[wv][0] = b0; xbs[wv][1] = b1; xbs[wv][2] = b2; xbs[wv][3] = b3; }
    }
    __syncthreads();
    int lo = 0;
#pragma unroll
    for (int t8 = 0; t8 < 8; ++t8) {
        int mm = 0;
#pragma unroll
        for (int w = 0; w < 4; ++w) mm += __popcll(xbs[t8][w] ^ w0[w]);
        float xw = ((float)(256 - 2 * mm) + bi) + bh;
        int T0 = (int)floor((512.0 + (double)xw) * 0.5);   // exact (<= 41 mantissa bits)
        if ((t8 & 1) == 0) lo = T0;
        else {
            int t = tg * 8 + t8;
            T0p[((size_t)b * 256 + (t >> 1)) * 512 + tid] = (lo & 0xffff) | (T0 << 16);
        }
    }
}

// ---------------- sequential scan: layer-1 lagged; 2 batches per block ----------------
// 1024 threads = 16 waves: waves 0-7 -> batch 2*blk, waves 8-15 -> batch 2*blk+1.
// Both groups share ONE barrier per phase (amortizes the ~900cyc fixed phase
// overhead over 2x the issue work). Phase p computes h0[p] and h1[p-1] from
// state published at the previous barrier. st[g][par][0..7]=h0, [8..15]=h1.
__global__ __attribute__((amdgpu_flat_work_group_size(1024, 1024), amdgpu_waves_per_eu(4, 4)))
void scan_kernel(const float* __restrict__ bih1, const float* __restrict__ bhh1,
                 const u64* __restrict__ u0b, const u64* __restrict__ w1b,
                 const u64* __restrict__ u1b, const u64* __restrict__ wfcb,
                 const int* __restrict__ T0d, float* __restrict__ out) {
    __shared__ __align__(16) u64 st[2][2][16];

    const int tid = threadIdx.x;
    const int g = tid >> 9;          // batch group within block
    const int stid = tid & 511;      // h unit
    const int batch = blockIdx.x * 2 + g;
    u64 u0[8], w1[8], u1[8];
#pragma unroll
    for (int w = 0; w < 8; ++w) u0[w] = opaque64(u0b[stid * 8 + w]);
#pragma unroll
    for (int w = 0; w < 8; ++w) w1[w] = opaque64(w1b[stid * 8 + w]);
#pragma unroll
    for (int w = 0; w < 8; ++w) u1[w] = opaque64(u1b[stid * 8 + w]);
    const float bi1 = bih1[stid], bh1 = bhh1[stid];
    const int lane = tid & 63;
    const int wv = stid >> 6;
    u64 (*stg)[16] = st[g];

    const int* T0row = T0d + (size_t)batch * (256 * 512) + stid;  // +512 per t-pair
    const int* Tlast = T0row + 255 * 512;   // last valid pair {t510,t511}
    int pc = T0row[0];          // pair {t0,t1}   (consumed in phases 0,1)
    int pn = T0row[512];        // pair {t2,t3}
    int p2 = T0row[1024];       // pair {t4,t5}
    const int* Tptr = T0row + 1536;

    // ---- phase 0: h0[0] (h0[-1]=0 -> condition 256 <= T0(t0)) ----
    {
        u64 b0 = __ballot(256 <= (int)(short)(pc & 0xffff));
        if (lane == 0) stg[0][wv] = b0;
        lds_barrier();
    }
    // ---- phase 1: h0[1] (T0(t1)); h1[0] with forced HU=0 (cmp c1 >= 0) ----
    {
        const ulonglong2* h0p = (const ulonglong2*)&stg[0][0];
        int mh0 = 0, mx1 = 0;
#pragma unroll
        for (int w = 0; w < 4; ++w) {
            ulonglong2 hv = h0p[w];
            mh0 += __popcll(hv.x ^ u0[2 * w]) + __popcll(hv.y ^ u0[2 * w + 1]);
            mx1 += __popcll(hv.x ^ w1[2 * w]) + __popcll(hv.y ^ w1[2 * w + 1]);
        }
        u64 b0 = __ballot(mh0 <= (int)(short)(pc >> 16));
        float c1 = ((float)(512 - 2 * mx1) + bi1) + bh1;
        u64 b1 = __ballot(c1 >= 0.0f);
        if (lane == 0) { stg[1][wv] = b0; stg[1][8 + wv] = b1; }
        lds_barrier();
    }

#define QRNN_PHASE(RD, WR, T0IMM)                                                   \
    {                                                                               \
        const ulonglong2* h0p = (const ulonglong2*)&stg[RD][0];                     \
        const ulonglong2* h1p = (const ulonglong2*)&stg[RD][8];                     \
        int mh0 = 0, mx1 = 0, mh1 = 0;                                              \
        _Pragma("unroll")                                                           \
        for (int w = 0; w < 4; ++w) {                                               \
            ulonglong2 hv = h0p[w];                                                 \
            mh0 += __popcll(hv.x ^ u0[2 * w]) + __popcll(hv.y ^ u0[2 * w + 1]);     \
            mx1 += __popcll(hv.x ^ w1[2 * w]) + __popcll(hv.y ^ w1[2 * w + 1]);     \
        }                                                                           \
        _Pragma("unroll")                                                           \
        for (int w = 0; w < 4; ++w) {                                               \
            ulonglong2 hv = h1p[w];                                                 \
            mh1 += __popcll(hv.x ^ u1[2 * w]) + __popcll(hv.y ^ u1[2 * w + 1]);     \
        }                                                                           \
        u64 b0 = __ballot(mh0 <= (int)(T0IMM));                                     \
        float c1 = ((float)(512 - 2 * mx1) + bi1) + bh1;                            \
        u64 b1 = __ballot(c1 >= (float)(2 * mh1 - 512));                            \
        if (lane == 0) { stg[WR][wv] = b0; stg[WR][8 + wv] = b1; }                  \
        lds_barrier();                                                              \
    }

    // ---- main loop: phases p (even, rd=1,wr=0) and p+1 (odd, rd=0,wr=1).
    // Iteration p consumes pn = pair {t_p, t_{p+1}}.
    for (int p = 2; p < 512; p += 2) {
        const int* tp = (Tptr > Tlast) ? Tlast : Tptr;   // clamp tail prefetch
        int pf = *tp; Tptr += 512;   // pair {t_{p+4}, t_{p+5}}
        QRNN_PHASE(1, 0, (short)(pn & 0xffff));
        QRNN_PHASE(0, 1, (short)(pn >> 16));
        pn = p2; p2 = pf;
    }
#undef QRNN_PHASE

    // ---- phase 512: h1[511] only (inputs h0[511], h1[510] in stg[1]) ----
    {
        const ulonglong2* h0p = (const ulonglong2*)&stg[1][0];
        const ulonglong2* h1p = (const ulonglong2*)&stg[1][8];
        int mx1 = 0, mh1 = 0;
#pragma unroll
        for (int w = 0; w < 4; ++w) {
            ulonglong2 hv = h0p[w];
            mx1 += __popcll(hv.x ^ w1[2 * w]) + __popcll(hv.y ^ w1[2 * w + 1]);
        }
#pragma unroll
        for (int w = 0; w < 4; ++w) {
            ulonglong2 hv = h1p[w];
            mh1 += __popcll(hv.x ^ u1[2 * w]) + __popcll(hv.y ^ u1[2 * w + 1]);
        }
        float c1 = ((float)(512 - 2 * mx1) + bi1) + bh1;
        u64 b1 = __ballot(c1 >= (float)(2 * mh1 - 512));
        if (lane == 0) stg[0][8 + wv] = b1;
        lds_barrier();
    }
    // ---- fused final dense: out[layer*64 + batch] = hT . sign(Wfc) ----
    if (stid < 2) {
        const u64* h = (stid == 0) ? &stg[1][0] : &stg[0][8];  // h0[511] / h1[511]
        int mm = 0;
#pragma unroll
        for (int w = 0; w < 8; ++w) mm += __popcll(h[w] ^ wfcb[w]);
        out[stid * 64 + batch] = (float)(512 - 2 * mm);
    }
}

extern "C" void kernel_launch(void* const* d_in, const int* in_sizes, int n_in,
                              void* d_out, int out_size, void* d_ws, size_t ws_size,
                              hipStream_t stream) {
    const int* text = (const int*)d_in[0];
    // d_in[1] = text_lengths : unused by the reference computation
    const float* emb = (const float*)d_in[2];
    const float* Wih0 = (const float*)d_in[3];
    const float* Whh0 = (const float*)d_in[4];
    const float* bih0 = (const float*)d_in[5];
    const float* bhh0 = (const float*)d_in[6];
    const float* Wih1 = (const float*)d_in[7];
    const float* Whh1 = (const float*)d_in[8];
    const float* bih1 = (const float*)d_in[9];
    const float* bhh1 = (const float*)d_in[10];
    const float* Wfc = (const float*)d_in[11];
    float* out = (float*)d_out;

    // workspace layout (u64 units)
    u64* ws = (u64*)d_ws;
    u64* w0b = ws + 8;             // 512*4 = 2048
    u64* u0b = w0b + 2048;         // 4096
    u64* w1b = u0b + 4096;         // 4096
    u64* u1b = w1b + 4096;         // 4096
    u64* wfcb = u1b + 4096;        // 8
    int* T0p = (int*)(wfcb + 8);   // 64*256*512 dwords = 32 MB
    unsigned int* amax = (unsigned int*)d_ws;

    hipMemsetAsync(d_ws, 0, 64, stream);  // amax := 0 (ws is poisoned 0xAA)
    pack_kernel<<<(897 * 64 + 255) / 256, 256, 0, stream>>>(Wih0, Whh0, Wih1, Whh1, Wfc,
                                                            w0b, u0b, w1b, u1b, wfcb);
    amax_kernel<<<2048, 256, 0, stream>>>(emb, amax);
    xw_kernel<<<64 * 64, 512, 0, stream>>>(text, bih0, bhh0, emb, amax, w0b, T0p);
    scan_kernel<<<32, 1024, 0, stream>>>(bih1, bhh1, u0b, w1b, u1b, wfcb, T0p, out);
}

// Round 7
// 525.100 us; speedup vs baseline: 1.3011x; 1.3011x over previous
//
#include <hip/hip_runtime.h>

typedef unsigned long long u64;

// Pass-through that makes the value asm-defined: the compiler cannot
// rematerialize the originating load inside the loop.
__device__ __forceinline__ u64 opaque64(u64 x) { asm volatile("" : "+v"(x)); return x; }

// Workgroup barrier that orders LDS only (no vmcnt drain).
__device__ __forceinline__ void lds_barrier() {
    asm volatile("s_waitcnt lgkmcnt(0)" ::: "memory");
    __builtin_amdgcn_s_barrier();
    asm volatile("" ::: "memory");
}

// ---------------- amax over |emb| ----------------
__global__ void amax_kernel(const float* __restrict__ emb, unsigned int* __restrict__ out) {
    const int n4 = (32000 * 256) / 4;
    float m = 0.0f;
    const float4* e4 = (const float4*)emb;
    for (int i = blockIdx.x * blockDim.x + threadIdx.x; i < n4; i += gridDim.x * blockDim.x) {
        float4 v = e4[i];
        m = fmaxf(m, fmaxf(fmaxf(fabsf(v.x), fabsf(v.y)), fmaxf(fabsf(v.z), fabsf(v.w))));
    }
#pragma unroll
    for (int off = 32; off > 0; off >>= 1) m = fmaxf(m, __shfl_down(m, off, 64));
    if ((threadIdx.x & 63) == 0) atomicMax(out, __float_as_uint(m));
}

// ---------------- weight bit packing ----------------
// One wave packs 16 words (1024 consecutive floats). Section boundaries
// {2048,6144,10240,14336} are multiples of 16; Wfc is the 8-word tail.
__global__ void pack_kernel(const float* __restrict__ Wih0, const float* __restrict__ Whh0,
                            const float* __restrict__ Wih1, const float* __restrict__ Whh1,
                            const float* __restrict__ Wfc,
                            u64* __restrict__ w0b, u64* __restrict__ u0b,
                            u64* __restrict__ w1b, u64* __restrict__ u1b, u64* __restrict__ wfcb) {
    const int gw = (blockIdx.x * blockDim.x + threadIdx.x) >> 6;  // global wave id
    const int lane = threadIdx.x & 63;
    if (gw >= 897) return;
    const int wb = gw * 16;  // first packed word of this chunk

    const float* srcb; u64* dstb; int nw = 16;
    if (wb < 2048)       { srcb = Wih0 + (long long)wb * 64;           dstb = w0b + wb; }
    else if (wb < 6144)  { srcb = Whh0 + (long long)(wb - 2048) * 64;  dstb = u0b + (wb - 2048); }
    else if (wb < 10240) { srcb = Wih1 + (long long)(wb - 6144) * 64;  dstb = w1b + (wb - 6144); }
    else if (wb < 14336) { srcb = Whh1 + (long long)(wb - 10240) * 64; dstb = u1b + (wb - 10240); }
    else                 { srcb = Wfc  + (long long)(wb - 14336) * 64; dstb = wfcb + (wb - 14336); nw = 8; }

    u64 mine = 0;
    for (int k0 = 0; k0 < nw; k0 += 8) {
        float v[8];
#pragma unroll
        for (int j = 0; j < 8; ++j) v[j] = srcb[(long long)(k0 + j) * 64 + lane];
#pragma unroll
        for (int j = 0; j < 8; ++j) {
            u64 bits = __ballot(v[j] >= 0.0f);
            if (lane == k0 + j) mine = bits;
        }
    }
    if (lane < nw) dstb[lane] = mine;   // coalesced 8B stores
}

// ---------------- wave-specialized sequential scan ----------------
// 64 blocks (1/batch, 1/CU) x 1024 threads = 16 waves (4/SIMD).
// Group A = waves 0-7 (512 threads): layer-0 update, incl. inline xW (mm0 vs
//   LDS-resident binarized embedding rows) and the layer-0 float chain.
// Group B = waves 8-15: layer-1 update (mx1 from h0, mh1 from h1).
// Both halves read only state published at the previous barrier => ONE
// barrier/phase, shared by both groups. Layer 1 lags layer 0 by one phase.
// st[par][0..7]=h0, st[par][8..15]=h1; phase p reads st[(p-1)&1], writes st[p&1].
__global__ __attribute__((amdgpu_flat_work_group_size(1024, 1024), amdgpu_waves_per_eu(4, 4)))
void scan_kernel(const int* __restrict__ text,
                 const float* __restrict__ bih0, const float* __restrict__ bhh0,
                 const float* __restrict__ bih1, const float* __restrict__ bhh1,
                 const float* __restrict__ emb, const unsigned int* __restrict__ amax_bits,
                 const u64* __restrict__ w0b, const u64* __restrict__ u0b,
                 const u64* __restrict__ w1b, const u64* __restrict__ u1b,
                 const u64* __restrict__ wfcb, float* __restrict__ out) {
    __shared__ int txt[512];
    __shared__ __align__(16) u64 xbs[512][4];   // binarized embedding rows (16 KB)
    __shared__ __align__(16) u64 st[2][16];

    const int tid = threadIdx.x;
    const int b = blockIdx.x;
    const int lane = tid & 63;
    const int wvAll = tid >> 6;      // 0..15
    const bool isA = tid < 512;
    const int stid = tid & 511;      // h unit within group
    const int wv = stid >> 6;        // state word index for this wave

    if (isA) txt[stid] = text[b * 512 + stid];

    // group-specific pinned weights + biases
    u64 w0[4], u0[8], w1[8], u1[8];
    float bi, bh;
    if (isA) {
#pragma unroll
        for (int w = 0; w < 4; ++w) w0[w] = opaque64(w0b[stid * 4 + w]);
#pragma unroll
        for (int w = 0; w < 8; ++w) u0[w] = opaque64(u0b[stid * 8 + w]);
        bi = bih0[stid]; bh = bhh0[stid];
    } else {
#pragma unroll
        for (int w = 0; w < 8; ++w) w1[w] = opaque64(w1b[stid * 8 + w]);
#pragma unroll
        for (int w = 0; w < 8; ++w) u1[w] = opaque64(u1b[stid * 8 + w]);
        bi = bih1[stid]; bh = bhh1[stid];
    }
    // binq threshold for int8-fixed-point emb: bit = rint(v/s)>=0 <=> v >= -s/2
    float amax = __uint_as_float(*amax_bits) + 1e-12f;
    float thr = -0.5f * exp2f(ceilf(log2f(amax / 127.0f)));   // s is a power of two

    lds_barrier();   // txt visible

    // Prologue: binarize this batch's 512 embedding rows into xbs.
    // Wave wvAll handles tokens wvAll*32 .. +31; coalesced 256B row-chunk reads.
#pragma unroll 2
    for (int k = 0; k < 32; ++k) {
        const int t = wvAll * 32 + k;
        const float* row = emb + (size_t)txt[t] * 256;
        float v0 = row[lane], v1 = row[64 + lane], v2 = row[128 + lane], v3 = row[192 + lane];
        u64 q0 = __ballot(v0 >= thr);
        u64 q1 = __ballot(v1 >= thr);
        u64 q2 = __ballot(v2 >= thr);
        u64 q3 = __ballot(v3 >= thr);
        if (lane == 0) { xbs[t][0] = q0; xbs[t][1] = q1; xbs[t][2] = q2; xbs[t][3] = q3; }
    }
    lds_barrier();   // xbs visible

    // --- phase macros (RD/WR/HAS* compile-time) ---
    // A: acc0 = fl(fl(fl((256-2mm0)+bih0)+bhh0) + (512-2mh0)), exact JAX association.
#define A_PHASE(RD, WR, TIDX, HASH)                                                 \
    {                                                                               \
        const ulonglong2* xp = (const ulonglong2*)xbs[TIDX];                        \
        ulonglong2 xv0 = xp[0], xv1 = xp[1];                                        \
        int mm0 = __popcll(xv0.x ^ w0[0]) + __popcll(xv0.y ^ w0[1])                 \
                + __popcll(xv1.x ^ w0[2]) + __popcll(xv1.y ^ w0[3]);                \
        float acc = ((float)(256 - 2 * mm0) + bi) + bh;                             \
        if (HASH) {                                                                 \
            const ulonglong2* h0p = (const ulonglong2*)&st[RD][0];                  \
            int mh0 = 0;                                                            \
            _Pragma("unroll")                                                       \
            for (int w = 0; w < 4; ++w) {                                           \
                ulonglong2 hv = h0p[w];                                             \
                mh0 += __popcll(hv.x ^ u0[2 * w]) + __popcll(hv.y ^ u0[2 * w + 1]); \
            }                                                                       \
            acc = acc + (float)(512 - 2 * mh0);                                     \
        }                                                                           \
        u64 bb = __ballot(acc >= 0.0f);                                             \
        if (lane == 0) st[WR][wv] = bb;                                             \
    }
    // B: h1[.] = sign(fl(c1 + (512-2mh1))), c1 = fl(fl((512-2mx1)+bih1)+bhh1).
#define B_PHASE(RD, WR, HASH1)                                                      \
    {                                                                               \
        const ulonglong2* h0p = (const ulonglong2*)&st[RD][0];                      \
        const ulonglong2* h1p = (const ulonglong2*)&st[RD][8];                      \
        int mx1 = 0, mh1 = 0;                                                       \
        _Pragma("unroll")                                                           \
        for (int w = 0; w < 4; ++w) {                                               \
            ulonglong2 hv = h0p[w];                                                 \
            mx1 += __popcll(hv.x ^ w1[2 * w]) + __popcll(hv.y ^ w1[2 * w + 1]);     \
        }                                                                           \
        _Pragma("unroll")                                                           \
        for (int w = 0; w < 4; ++w) {                                               \
            ulonglong2 hv = h1p[w];                                                 \
            mh1 += __popcll(hv.x ^ u1[2 * w]) + __popcll(hv.y ^ u1[2 * w + 1]);     \
        }                                                                           \
        float c1 = ((float)(512 - 2 * mx1) + bi) + bh;                              \
        float rhs = (HASH1) ? (float)(2 * mh1 - 512) : 0.0f;                        \
        u64 bb = __ballot(c1 >= rhs);                                               \
        if (lane == 0) st[WR][8 + wv] = bb;                                         \
    }

    // phase 0: h0[0] (h = 0 -> HU skipped); B idle
    if (isA) A_PHASE(0, 0, 0, false);
    lds_barrier();
    // phase 1: h0[1]; h1[0] with forced HU=0
    if (isA) { A_PHASE(0, 1, 1, true); } else { B_PHASE(0, 1, false); }
    lds_barrier();
    // main loop: phases p (even: rd=1,wr=0) and p+1 (odd: rd=0,wr=1)
    for (int p = 2; p < 512; p += 2) {
        if (isA) { A_PHASE(1, 0, p, true); } else { B_PHASE(1, 0, true); }
        lds_barrier();
        if (isA) { A_PHASE(0, 1, p + 1, true); } else { B_PHASE(0, 1, true); }
        lds_barrier();
    }
    // phase 512: h1[511] only (inputs h0[511], h1[510] in st[1])
    if (!isA) B_PHASE(1, 0, true);
    lds_barrier();
#undef A_PHASE
#undef B_PHASE

    // fused final dense: out[layer*64 + b] = hT . sign(Wfc)
    if (tid < 2) {
        const u64* h = (tid == 0) ? &st[1][0] : &st[0][8];  // h0[511] / h1[511]
        int mm = 0;
#pragma unroll
        for (int w = 0; w < 8; ++w) mm += __popcll(h[w] ^ wfcb[w]);
        out[tid * 64 + b] = (float)(512 - 2 * mm);
    }
}

extern "C" void kernel_launch(void* const* d_in, const int* in_sizes, int n_in,
                              void* d_out, int out_size, void* d_ws, size_t ws_size,
                              hipStream_t stream) {
    const int* text = (const int*)d_in[0];
    // d_in[1] = text_lengths : unused by the reference computation
    const float* emb = (const float*)d_in[2];
    const float* Wih0 = (const float*)d_in[3];
    const float* Whh0 = (const float*)d_in[4];
    const float* bih0 = (const float*)d_in[5];
    const float* bhh0 = (const float*)d_in[6];
    const float* Wih1 = (const float*)d_in[7];
    const float* Whh1 = (const float*)d_in[8];
    const float* bih1 = (const float*)d_in[9];
    const float* bhh1 = (const float*)d_in[10];
    const float* Wfc = (const float*)d_in[11];
    float* out = (float*)d_out;

    // workspace layout (u64 units)
    u64* ws = (u64*)d_ws;
    u64* w0b = ws + 8;             // 512*4 = 2048
    u64* u0b = w0b + 2048;         // 4096
    u64* w1b = u0b + 4096;         // 4096
    u64* u1b = w1b + 4096;         // 4096
    u64* wfcb = u1b + 4096;        // 8
    unsigned int* amax = (unsigned int*)d_ws;

    hipMemsetAsync(d_ws, 0, 64, stream);  // amax := 0 (ws is poisoned 0xAA)
    pack_kernel<<<(897 * 64 + 255) / 256, 256, 0, stream>>>(Wih0, Whh0, Wih1, Whh1, Wfc,
                                                            w0b, u0b, w1b, u1b, wfcb);
    amax_kernel<<<2048, 256, 0, stream>>>(emb, amax);
    scan_kernel<<<64, 1024, 0, stream>>>(text, bih0, bhh0, bih1, bhh1, emb, amax,
                                         w0b, u0b, w1b, u1b, wfcb, out);
}

// Round 8
// 521.483 us; speedup vs baseline: 1.3101x; 1.0069x over previous
//
#include <hip/hip_runtime.h>

typedef unsigned long long u64;

// Pass-through that makes the value asm-defined: the compiler cannot
// rematerialize the originating load inside the loop.
__device__ __forceinline__ u64 opaque64(u64 x) { asm volatile("" : "+v"(x)); return x; }

// Workgroup barrier that orders LDS only (no vmcnt drain).
__device__ __forceinline__ void lds_barrier() {
    asm volatile("s_waitcnt lgkmcnt(0)" ::: "memory");
    __builtin_amdgcn_s_barrier();
    asm volatile("" ::: "memory");
}

// ---------------- prep: weight bit-pack (blocks 0..224) + amax partials (225..480) ----------------
// Pack: one wave packs 16 u64 words (1024 consecutive floats); section
// boundaries {2048,6144,10240,14336} are multiples of 16; Wfc = 8-word tail.
// Amax: 256 blocks scan 8000 float4 each; one partial per wave (no atomics,
// no memset needed -- partials are plain-stored every launch).
__global__ void prep_kernel(const float* __restrict__ Wih0, const float* __restrict__ Whh0,
                            const float* __restrict__ Wih1, const float* __restrict__ Whh1,
                            const float* __restrict__ Wfc, const float* __restrict__ emb,
                            u64* __restrict__ w0b, u64* __restrict__ u0b,
                            u64* __restrict__ w1b, u64* __restrict__ u1b,
                            u64* __restrict__ wfcb, float* __restrict__ partials) {
    const int blk = blockIdx.x;
    const int lane = threadIdx.x & 63;
    if (blk < 225) {
        const int gw = (blk * 256 + threadIdx.x) >> 6;  // global wave id
        if (gw >= 897) return;
        const int wb = gw * 16;  // first packed word of this chunk
        const float* srcb; u64* dstb; int nw = 16;
        if (wb < 2048)       { srcb = Wih0 + (long long)wb * 64;           dstb = w0b + wb; }
        else if (wb < 6144)  { srcb = Whh0 + (long long)(wb - 2048) * 64;  dstb = u0b + (wb - 2048); }
        else if (wb < 10240) { srcb = Wih1 + (long long)(wb - 6144) * 64;  dstb = w1b + (wb - 6144); }
        else if (wb < 14336) { srcb = Whh1 + (long long)(wb - 10240) * 64; dstb = u1b + (wb - 10240); }
        else                 { srcb = Wfc  + (long long)(wb - 14336) * 64; dstb = wfcb + (wb - 14336); nw = 8; }
        u64 mine = 0;
        for (int k0 = 0; k0 < nw; k0 += 8) {
            float v[8];
#pragma unroll
            for (int j = 0; j < 8; ++j) v[j] = srcb[(long long)(k0 + j) * 64 + lane];
#pragma unroll
            for (int j = 0; j < 8; ++j) {
                u64 bits = __ballot(v[j] >= 0.0f);
                if (lane == k0 + j) mine = bits;
            }
        }
        if (lane < nw) dstb[lane] = mine;   // coalesced 8B stores
    } else {
        const int ab = blk - 225;           // 0..255
        const float4* e4 = (const float4*)emb + (long long)ab * 8000;
        float m = 0.0f;
        for (int i = threadIdx.x; i < 8000; i += 256) {
            float4 v = e4[i];
            m = fmaxf(m, fmaxf(fmaxf(fabsf(v.x), fabsf(v.y)), fmaxf(fabsf(v.z), fabsf(v.w))));
        }
#pragma unroll
        for (int off = 32; off > 0; off >>= 1) m = fmaxf(m, __shfl_down(m, off, 64));
        if (lane == 0) partials[ab * 4 + (threadIdx.x >> 6)] = m;  // 1024 partials
    }
}

// ---------------- sequential scan: 4 waves, 2 h-units/thread, layer-1 lagged ----------------
// 64 blocks (1/batch, 1/CU) x 256 threads (1 wave/SIMD). Thread k owns h-units
// k and k+256 of BOTH layers (56 pinned u64 weight words = 112 VGPRs;
// waves_per_eu(1,2) unlocks the 512-VGPR budget). Phase p computes h0[p] and
// h1[p-1], both from state published at the previous barrier => ONE
// lds_barrier/phase. State: st[par][0..7]=h0, [8..15]=h1 (standard word=u>>6
// packing: ballot(bit of unit k)=word wv, ballot(unit k+256)=word 4+wv).
// xbs token bits prefetched one phase ahead into registers.
__global__ __attribute__((amdgpu_flat_work_group_size(256, 256), amdgpu_waves_per_eu(1, 2)))
void scan_kernel(const int* __restrict__ text,
                 const float* __restrict__ bih0, const float* __restrict__ bhh0,
                 const float* __restrict__ bih1, const float* __restrict__ bhh1,
                 const float* __restrict__ emb, const float* __restrict__ partials,
                 const u64* __restrict__ w0b, const u64* __restrict__ u0b,
                 const u64* __restrict__ w1b, const u64* __restrict__ u1b,
                 const u64* __restrict__ wfcb, float* __restrict__ out) {
    __shared__ int txt[512];
    __shared__ __align__(16) u64 xbs[512][4];   // binarized embedding rows (16 KB)
    __shared__ __align__(16) u64 st[2][16];

    const int tid = threadIdx.x;
    const int b = blockIdx.x;
    const int lane = tid & 63;
    const int wv = tid >> 6;    // wave id 0..3

    txt[tid] = text[b * 512 + tid];
    txt[tid + 256] = text[b * 512 + tid + 256];

    // amax reduce -> binq threshold: bit = rint(v/s)>=0 <=> v >= -s/2 (s = 2^e)
    float m = 0.0f;
#pragma unroll
    for (int j = 0; j < 16; ++j) m = fmaxf(m, partials[lane + 64 * j]);
#pragma unroll
    for (int off = 32; off > 0; off >>= 1) m = fmaxf(m, __shfl_xor(m, off));
    const float amax = m + 1e-12f;
    const float thr = -0.5f * exp2f(ceilf(log2f(amax / 127.0f)));

    // pinned per-thread weight rows for units ua=tid, ub=tid+256
    u64 w0[2][4], u0[2][8], w1[2][8], u1[2][8];
    float bi0[2], bh0[2], bi1[2], bh1[2];
#pragma unroll
    for (int q = 0; q < 2; ++q) {
        const int u = tid + q * 256;
#pragma unroll
        for (int w = 0; w < 4; ++w) w0[q][w] = opaque64(w0b[u * 4 + w]);
#pragma unroll
        for (int w = 0; w < 8; ++w) u0[q][w] = opaque64(u0b[u * 8 + w]);
#pragma unroll
        for (int w = 0; w < 8; ++w) w1[q][w] = opaque64(w1b[u * 8 + w]);
#pragma unroll
        for (int w = 0; w < 8; ++w) u1[q][w] = opaque64(u1b[u * 8 + w]);
        bi0[q] = bih0[u]; bh0[q] = bhh0[u];
        bi1[q] = bih1[u]; bh1[q] = bhh1[u];
    }

    lds_barrier();   // txt visible

    // binarize this batch's 512 embedding rows: wave wv -> tokens [wv*128, +128)
    for (int k = 0; k < 128; ++k) {
        const int t = wv * 128 + k;
        const float* row = emb + (size_t)txt[t] * 256;
        float v0 = row[lane], v1 = row[64 + lane], v2 = row[128 + lane], v3 = row[192 + lane];
        u64 q0 = __ballot(v0 >= thr);
        u64 q1 = __ballot(v1 >= thr);
        u64 q2 = __ballot(v2 >= thr);
        u64 q3 = __ballot(v3 >= thr);
        if (lane == 0) { xbs[t][0] = q0; xbs[t][1] = q1; xbs[t][2] = q2; xbs[t][3] = q3; }
    }
    lds_barrier();   // xbs visible

    u64 xv[4], xn[4];
#define LDX(T) { const ulonglong2* _xp = (const ulonglong2*)xbs[(T)];               \
                 ulonglong2 _xa = _xp[0], _xb = _xp[1];                             \
                 xn[0] = _xa.x; xn[1] = _xa.y; xn[2] = _xb.x; xn[3] = _xb.y; }
#define XSWAP { xv[0] = xn[0]; xv[1] = xn[1]; xv[2] = xn[2]; xv[3] = xn[3]; }

    { LDX(0) XSWAP }

    // PHASE: h0 update for units {tid, tid+256} (+ optional HU term), h1 update
    // (optional), exact JAX association: acc0 = fl(fl(fl((256-2mm0)+bi0)+bh0)+(512-2mh0));
    // h1: fl(c1+(512-2mh1))>=0 <=> c1 >= (float)(2mh1-512)  [exact, verified R5-R7].
#define PHASE(RD, WR, H0HU, DOH1, H1HU)                                             \
    {                                                                               \
        const ulonglong2* _h0p = (const ulonglong2*)&st[RD][0];                     \
        ulonglong2 _ha = _h0p[0], _hb = _h0p[1], _hc = _h0p[2], _hd = _h0p[3];      \
        ulonglong2 _e0, _e1, _e2, _e3;                                              \
        if (DOH1 && H1HU) {                                                         \
            const ulonglong2* _h1p = (const ulonglong2*)&st[RD][8];                 \
            _e0 = _h1p[0]; _e1 = _h1p[1]; _e2 = _h1p[2]; _e3 = _h1p[3];             \
        }                                                                           \
        bool _p0[2], _p1[2];                                                        \
        _Pragma("unroll")                                                           \
        for (int _q = 0; _q < 2; ++_q) {                                            \
            int _mm0 = __popcll(xv[0] ^ w0[_q][0]) + __popcll(xv[1] ^ w0[_q][1])    \
                     + __popcll(xv[2] ^ w0[_q][2]) + __popcll(xv[3] ^ w0[_q][3]);   \
            float _acc = ((float)(256 - 2 * _mm0) + bi0[_q]) + bh0[_q];             \
            if (H0HU) {                                                             \
                int _mh0 = __popcll(_ha.x ^ u0[_q][0]) + __popcll(_ha.y ^ u0[_q][1])\
                         + __popcll(_hb.x ^ u0[_q][2]) + __popcll(_hb.y ^ u0[_q][3])\
                         + __popcll(_hc.x ^ u0[_q][4]) + __popcll(_hc.y ^ u0[_q][5])\
                         + __popcll(_hd.x ^ u0[_q][6]) + __popcll(_hd.y ^ u0[_q][7]);\
                _acc = _acc + (float)(512 - 2 * _mh0);                              \
            }                                                                       \
            _p0[_q] = _acc >= 0.0f;                                                 \
            if (DOH1) {                                                             \
                int _mx1 = __popcll(_ha.x ^ w1[_q][0]) + __popcll(_ha.y ^ w1[_q][1])\
                         + __popcll(_hb.x ^ w1[_q][2]) + __popcll(_hb.y ^ w1[_q][3])\
                         + __popcll(_hc.x ^ w1[_q][4]) + __popcll(_hc.y ^ w1[_q][5])\
                         + __popcll(_hd.x ^ w1[_q][6]) + __popcll(_hd.y ^ w1[_q][7]);\
                float _c1 = ((float)(512 - 2 * _mx1) + bi1[_q]) + bh1[_q];          \
                float _rhs = 0.0f;                                                  \
                if (H1HU) {                                                         \
                    int _mh1 = __popcll(_e0.x ^ u1[_q][0]) + __popcll(_e0.y ^ u1[_q][1])\
                             + __popcll(_e1.x ^ u1[_q][2]) + __popcll(_e1.y ^ u1[_q][3])\
                             + __popcll(_e2.x ^ u1[_q][4]) + __popcll(_e2.y ^ u1[_q][5])\
                             + __popcll(_e3.x ^ u1[_q][6]) + __popcll(_e3.y ^ u1[_q][7]);\
                    _rhs = (float)(2 * _mh1 - 512);                                 \
                }                                                                   \
                _p1[_q] = _c1 >= _rhs;                                              \
            }                                                                       \
        }                                                                           \
        u64 _b0l = __ballot(_p0[0]), _b0h = __ballot(_p0[1]);                       \
        if (lane == 0) { st[WR][wv] = _b0l; st[WR][4 + wv] = _b0h; }                \
        if (DOH1) {                                                                 \
            u64 _b1l = __ballot(_p1[0]), _b1h = __ballot(_p1[1]);                   \
            if (lane == 0) { st[WR][8 + wv] = _b1l; st[WR][12 + wv] = _b1h; }       \
        }                                                                           \
    }

    // phase 0: h0[0] (h=0 -> no HU), no h1
    PHASE(0, 0, false, false, false)
    LDX(1)
    lds_barrier(); XSWAP
    // phase 1: h0[1]; h1[0] with forced HU=0
    PHASE(0, 1, true, true, false)
    LDX(2)
    lds_barrier(); XSWAP
    // main loop: phases p (even: rd=1,wr=0) and p+1 (odd: rd=0,wr=1)
    for (int p = 2; p < 512; p += 2) {
        PHASE(1, 0, true, true, true)
        LDX(p + 1)
        lds_barrier(); XSWAP
        PHASE(0, 1, true, true, true)
        const int tnx = (p + 2 < 512) ? p + 2 : 511;
        LDX(tnx)
        lds_barrier(); XSWAP
    }
    // phase 512: h1[511] -> st[0][8..15] (h0 part of the write is junk, unused)
    PHASE(1, 0, true, true, true)
    lds_barrier();
#undef PHASE
#undef LDX
#undef XSWAP

    // fused final dense: out[layer*64 + b] = hT . sign(Wfc)
    if (tid < 2) {
        const u64* h = (tid == 0) ? &st[1][0] : &st[0][8];  // h0[511] / h1[511]
        int mm = 0;
#pragma unroll
        for (int w = 0; w < 8; ++w) mm += __popcll(h[w] ^ wfcb[w]);
        out[tid * 64 + b] = (float)(512 - 2 * mm);
    }
}

extern "C" void kernel_launch(void* const* d_in, const int* in_sizes, int n_in,
                              void* d_out, int out_size, void* d_ws, size_t ws_size,
                              hipStream_t stream) {
    const int* text = (const int*)d_in[0];
    // d_in[1] = text_lengths : unused by the reference computation
    const float* emb = (const float*)d_in[2];
    const float* Wih0 = (const float*)d_in[3];
    const float* Whh0 = (const float*)d_in[4];
    const float* bih0 = (const float*)d_in[5];
    const float* bhh0 = (const float*)d_in[6];
    const float* Wih1 = (const float*)d_in[7];
    const float* Whh1 = (const float*)d_in[8];
    const float* bih1 = (const float*)d_in[9];
    const float* bhh1 = (const float*)d_in[10];
    const float* Wfc = (const float*)d_in[11];
    float* out = (float*)d_out;

    // workspace layout (u64 units)
    u64* ws = (u64*)d_ws;
    u64* w0b = ws;                  // 512*4 = 2048
    u64* u0b = w0b + 2048;          // 4096
    u64* w1b = u0b + 4096;          // 4096
    u64* u1b = w1b + 4096;          // 4096
    u64* wfcb = u1b + 4096;         // 8
    float* partials = (float*)(wfcb + 8);   // 1024 floats

    prep_kernel<<<481, 256, 0, stream>>>(Wih0, Whh0, Wih1, Whh1, Wfc, emb,
                                         w0b, u0b, w1b, u1b, wfcb, partials);
    scan_kernel<<<64, 256, 0, stream>>>(text, bih0, bhh0, bih1, bhh1, emb, partials,
                                        w0b, u0b, w1b, u1b, wfcb, out);
}

// Round 9
// 398.825 us; speedup vs baseline: 1.7131x; 1.3076x over previous
//
#include <hip/hip_runtime.h>

typedef unsigned long long u64;

// Pass-through that makes the value asm-defined: the compiler cannot
// rematerialize the originating load inside the loop.
__device__ __forceinline__ u64 opaque64(u64 x) { asm volatile("" : "+v"(x)); return x; }

// Workgroup barrier that orders LDS only (no vmcnt drain), so global-memory
// prefetch loads stay in flight across it.
__device__ __forceinline__ void lds_barrier() {
    asm volatile("s_waitcnt lgkmcnt(0)" ::: "memory");
    __builtin_amdgcn_s_barrier();
    asm volatile("" ::: "memory");
}

// ---------------- prep: weight bit-pack (blocks 0..224) + amax partials (225..480) ----------------
__global__ void prep_kernel(const float* __restrict__ Wih0, const float* __restrict__ Whh0,
                            const float* __restrict__ Wih1, const float* __restrict__ Whh1,
                            const float* __restrict__ Wfc, const float* __restrict__ emb,
                            u64* __restrict__ w0b, u64* __restrict__ u0b,
                            u64* __restrict__ w1b, u64* __restrict__ u1b,
                            u64* __restrict__ wfcb, float* __restrict__ partials) {
    const int blk = blockIdx.x;
    const int lane = threadIdx.x & 63;
    if (blk < 225) {
        const int gw = (blk * 256 + threadIdx.x) >> 6;  // global wave id
        if (gw >= 897) return;
        const int wb = gw * 16;  // first packed word of this chunk
        const float* srcb; u64* dstb; int nw = 16;
        if (wb < 2048)       { srcb = Wih0 + (long long)wb * 64;           dstb = w0b + wb; }
        else if (wb < 6144)  { srcb = Whh0 + (long long)(wb - 2048) * 64;  dstb = u0b + (wb - 2048); }
        else if (wb < 10240) { srcb = Wih1 + (long long)(wb - 6144) * 64;  dstb = w1b + (wb - 6144); }
        else if (wb < 14336) { srcb = Whh1 + (long long)(wb - 10240) * 64; dstb = u1b + (wb - 10240); }
        else                 { srcb = Wfc  + (long long)(wb - 14336) * 64; dstb = wfcb + (wb - 14336); nw = 8; }
        u64 mine = 0;
        for (int k0 = 0; k0 < nw; k0 += 8) {
            float v[8];
#pragma unroll
            for (int j = 0; j < 8; ++j) v[j] = srcb[(long long)(k0 + j) * 64 + lane];
#pragma unroll
            for (int j = 0; j < 8; ++j) {
                u64 bits = __ballot(v[j] >= 0.0f);
                if (lane == k0 + j) mine = bits;
            }
        }
        if (lane < nw) dstb[lane] = mine;   // coalesced 8B stores
    } else {
        const int ab = blk - 225;           // 0..255
        const float4* e4 = (const float4*)emb + (long long)ab * 8000;
        float m = 0.0f;
        for (int i = threadIdx.x; i < 8000; i += 256) {
            float4 v = e4[i];
            m = fmaxf(m, fmaxf(fmaxf(fabsf(v.x), fabsf(v.y)), fmaxf(fabsf(v.z), fabsf(v.w))));
        }
#pragma unroll
        for (int off = 32; off > 0; off >>= 1) m = fmaxf(m, __shfl_down(m, off, 64));
        if (lane == 0) partials[ab * 4 + (threadIdx.x >> 6)] = m;  // 1024 partials
    }
}

// ---------------- layer-0 input-threshold precompute (emb binarized inline) ----------------
// T0[b][t][h] = floor((512 + xw)/2), xw = fl(fl((256-2*mm0)+bih0)+bhh0).
// Exact: sign(fl(xw + (512-2*mh0))) >= 0  <=>  mh0 <= T0   (h=0 case: mh0:=256).
// Stored as i16 pairs: dword (b*256 + t/2)*512 + h holds {t even, t odd}.
// Block (b,tg) covers t = tg*8..tg*8+7; wave wv binarizes token tg*8+wv's row.
__global__ void xw_kernel(const int* __restrict__ text,
                          const float* __restrict__ bih0, const float* __restrict__ bhh0,
                          const float* __restrict__ emb, const float* __restrict__ partials,
                          const u64* __restrict__ w0b, int* __restrict__ T0p) {
    const int tid = threadIdx.x;
    const int lane = tid & 63;
    const int wv = tid >> 6;      // 0..7
    const int b = blockIdx.x >> 6;
    const int tg = blockIdx.x & 63;
    __shared__ __align__(16) u64 xbs[8][4];

    // amax reduce -> threshold: bit = rint(v/s)>=0 <=> v >= -s/2 (s = 2^e exact)
    float m = 0.0f;
#pragma unroll
    for (int j = 0; j < 16; ++j) m = fmaxf(m, partials[lane + 64 * j]);
#pragma unroll
    for (int off = 32; off > 0; off >>= 1) m = fmaxf(m, __shfl_xor(m, off));
    const float thr = -0.5f * exp2f(ceilf(log2f((m + 1e-12f) / 127.0f)));

    {   // wave wv binarizes the row of token t = tg*8+wv (coalesced 256B chunks)
        const int tok = text[b * 512 + tg * 8 + wv];
        const float* row = emb + (size_t)tok * 256;
        float v0 = row[lane], v1 = row[64 + lane], v2 = row[128 + lane], v3 = row[192 + lane];
        u64 q0 = __ballot(v0 >= thr);
        u64 q1 = __ballot(v1 >= thr);
        u64 q2 = __ballot(v2 >= thr);
        u64 q3 = __ballot(v3 >= thr);
        if (lane == 0) { xbs[wv][0] = q0; xbs[wv][1] = q1; xbs[wv][2] = q2; xbs[wv][3] = q3; }
    }
    u64 w0[4];
#pragma unroll
    for (int w = 0; w < 4; ++w) w0[w] = w0b[tid * 4 + w];
    const float bi = bih0[tid], bh = bhh0[tid];
    __syncthreads();

    int lo = 0;
#pragma unroll
    for (int t8 = 0; t8 < 8; ++t8) {
        int mm = 0;
#pragma unroll
        for (int w = 0; w < 4; ++w) mm += __popcll(xbs[t8][w] ^ w0[w]);
        float xw = ((float)(256 - 2 * mm) + bi) + bh;
        int T0 = (int)floor((512.0 + (double)xw) * 0.5);   // exact (<= 41 mantissa bits)
        if ((t8 & 1) == 0) lo = T0;
        else {
            int t = tg * 8 + t8;
            T0p[((size_t)b * 256 + (t >> 1)) * 512 + tid] = (lo & 0xffff) | (T0 << 16);
        }
    }
}

// ---------------- sequential scan: layer-1 lagged one step; interleaved state ----------------
// 64 blocks (1/batch) x 512 threads (8 waves, 2/SIMD). Thread = one h unit of
// both layers; pinned weights u0,w1,u1 = 24 u64 = 48 VGPR (proven <= 88 cap).
// State: st[par][w] = {h0_word_w, h1_word_w}; phase p reads st[(p-1)&1],
// writes st[p&1] -- lane0 publishes BOTH ballots with one ds_write_b128.
// Layer-0 update is an integer threshold test vs the precomputed T0 stream
// (vector loads, prefetched 2 iterations ahead, vmcnt-immune to lds_barrier).
__global__ __attribute__((amdgpu_flat_work_group_size(512, 512), amdgpu_waves_per_eu(2, 2)))
void scan_kernel(const float* __restrict__ bih1, const float* __restrict__ bhh1,
                 const u64* __restrict__ u0b, const u64* __restrict__ w1b,
                 const u64* __restrict__ u1b, const u64* __restrict__ wfcb,
                 const int* __restrict__ T0d, float* __restrict__ out) {
    __shared__ __align__(16) ulonglong2 st[2][8];

    const int tid = threadIdx.x;
    const int b = blockIdx.x;
    const int lane = tid & 63;
    const int wv = tid >> 6;

    u64 u0[8], w1[8], u1[8];
#pragma unroll
    for (int w = 0; w < 8; ++w) u0[w] = opaque64(u0b[tid * 8 + w]);
#pragma unroll
    for (int w = 0; w < 8; ++w) w1[w] = opaque64(w1b[tid * 8 + w]);
#pragma unroll
    for (int w = 0; w < 8; ++w) u1[w] = opaque64(u1b[tid * 8 + w]);
    const float bi1 = bih1[tid], bh1 = bhh1[tid];

    const int* T0row = T0d + (size_t)b * (256 * 512) + tid;  // +512 per t-pair
    const int* Tlast = T0row + 255 * 512;   // last valid pair {t510,t511}
    int pc = T0row[0];          // pair {t0,t1}   (consumed in phases 0,1)
    int pn = T0row[512];        // pair {t2,t3}
    int p2 = T0row[1024];       // pair {t4,t5}
    const int* Tptr = T0row + 1536;

    // ---- phase 0: h0[0] (h0[-1]=0 -> condition 256 <= T0(t0)); h1 word junk ----
    {
        u64 b0 = __ballot(256 <= (int)(short)(pc & 0xffff));
        if (lane == 0) { ulonglong2 v; v.x = b0; v.y = 0; st[0][wv] = v; }
        lds_barrier();
    }
    // ---- phase 1: h0[1] (T0(t1)); h1[0] with forced HU=0 (reads .x only) ----
    {
        ulonglong2 s0 = st[0][0], s1 = st[0][1], s2 = st[0][2], s3 = st[0][3],
                   s4 = st[0][4], s5 = st[0][5], s6 = st[0][6], s7 = st[0][7];
        int mh0 = __popcll(s0.x ^ u0[0]) + __popcll(s1.x ^ u0[1]) + __popcll(s2.x ^ u0[2])
                + __popcll(s3.x ^ u0[3]) + __popcll(s4.x ^ u0[4]) + __popcll(s5.x ^ u0[5])
                + __popcll(s6.x ^ u0[6]) + __popcll(s7.x ^ u0[7]);
        int mx1 = __popcll(s0.x ^ w1[0]) + __popcll(s1.x ^ w1[1]) + __popcll(s2.x ^ w1[2])
                + __popcll(s3.x ^ w1[3]) + __popcll(s4.x ^ w1[4]) + __popcll(s5.x ^ w1[5])
                + __popcll(s6.x ^ w1[6]) + __popcll(s7.x ^ w1[7]);
        u64 b0 = __ballot(mh0 <= (int)(short)(pc >> 16));
        float c1 = ((float)(512 - 2 * mx1) + bi1) + bh1;
        u64 b1 = __ballot(c1 >= 0.0f);
        if (lane == 0) { ulonglong2 v; v.x = b0; v.y = b1; st[1][wv] = v; }
        lds_barrier();
    }

    // PHASE: h0 threshold test + h1 float chain, exact JAX association (R5-verified):
    // h0: mh0 <= T0; h1: fl(c1+(512-2mh1))>=0 <=> c1 >= (float)(2mh1-512).
#define PHASE(RD, WR, T0IMM)                                                        \
    {                                                                               \
        ulonglong2 s0 = st[RD][0], s1 = st[RD][1], s2 = st[RD][2], s3 = st[RD][3],  \
                   s4 = st[RD][4], s5 = st[RD][5], s6 = st[RD][6], s7 = st[RD][7];  \
        int mh0 = __popcll(s0.x ^ u0[0]) + __popcll(s1.x ^ u0[1])                   \
                + __popcll(s2.x ^ u0[2]) + __popcll(s3.x ^ u0[3])                   \
                + __popcll(s4.x ^ u0[4]) + __popcll(s5.x ^ u0[5])                   \
                + __popcll(s6.x ^ u0[6]) + __popcll(s7.x ^ u0[7]);                  \
        int mx1 = __popcll(s0.x ^ w1[0]) + __popcll(s1.x ^ w1[1])                   \
                + __popcll(s2.x ^ w1[2]) + __popcll(s3.x ^ w1[3])                   \
                + __popcll(s4.x ^ w1[4]) + __popcll(s5.x ^ w1[5])                   \
                + __popcll(s6.x ^ w1[6]) + __popcll(s7.x ^ w1[7]);                  \
        int mh1 = __popcll(s0.y ^ u1[0]) + __popcll(s1.y ^ u1[1])                   \
                + __popcll(s2.y ^ u1[2]) + __popcll(s3.y ^ u1[3])                   \
                + __popcll(s4.y ^ u1[4]) + __popcll(s5.y ^ u1[5])                   \
                + __popcll(s6.y ^ u1[6]) + __popcll(s7.y ^ u1[7]);                  \
        u64 b0 = __ballot(mh0 <= (int)(T0IMM));                                     \
        float c1 = ((float)(512 - 2 * mx1) + bi1) + bh1;                            \
        u64 b1 = __ballot(c1 >= (float)(2 * mh1 - 512));                            \
        if (lane == 0) { ulonglong2 v; v.x = b0; v.y = b1; st[WR][wv] = v; }        \
        lds_barrier();                                                              \
    }

    // main loop: phases p (even: rd=1,wr=0) and p+1 (odd: rd=0,wr=1).
    // Iteration p consumes pn = pair {t_p, t_{p+1}}.
    for (int p = 2; p < 512; p += 2) {
        const int* tp = (Tptr > Tlast) ? Tlast : Tptr;   // clamp tail prefetch
        int pf = *tp; Tptr += 512;   // pair {t_{p+4}, t_{p+5}}
        PHASE(1, 0, (short)(pn & 0xffff));
        PHASE(0, 1, (short)(pn >> 16));
        pn = p2; p2 = pf;
    }
    // phase 512: h1[511] only; reuses the macro (h0 part is junk, overwrites the
    // dead h0[510] word in st[0]); reads h0[511], h1[510] from st[1].
    PHASE(1, 0, 0);
#undef PHASE

    // fused final dense: out[layer*64 + b] = hT . sign(Wfc)
    if (tid < 2) {
        int mm = 0;
#pragma unroll
        for (int w = 0; w < 8; ++w) {
            u64 hw = (tid == 0) ? st[1][w].x : st[0][w].y;  // h0[511] / h1[511]
            mm += __popcll(hw ^ wfcb[w]);
        }
        out[tid * 64 + b] = (float)(512 - 2 * mm);
    }
}

extern "C" void kernel_launch(void* const* d_in, const int* in_sizes, int n_in,
                              void* d_out, int out_size, void* d_ws, size_t ws_size,
                              hipStream_t stream) {
    const int* text = (const int*)d_in[0];
    // d_in[1] = text_lengths : unused by the reference computation
    const float* emb = (const float*)d_in[2];
    const float* Wih0 = (const float*)d_in[3];
    const float* Whh0 = (const float*)d_in[4];
    const float* bih0 = (const float*)d_in[5];
    const float* bhh0 = (const float*)d_in[6];
    const float* Wih1 = (const float*)d_in[7];
    const float* Whh1 = (const float*)d_in[8];
    const float* bih1 = (const float*)d_in[9];
    const float* bhh1 = (const float*)d_in[10];
    const float* Wfc = (const float*)d_in[11];
    float* out = (float*)d_out;

    // workspace layout (u64 units)
    u64* ws = (u64*)d_ws;
    u64* w0b = ws;                  // 512*4 = 2048
    u64* u0b = w0b + 2048;          // 4096
    u64* w1b = u0b + 4096;          // 4096
    u64* u1b = w1b + 4096;          // 4096
    u64* wfcb = u1b + 4096;         // 8
    float* partials = (float*)(wfcb + 8);    // 1024 floats = 512 u64
    int* T0p = (int*)(partials + 1024);      // 64*256*512 dwords = 32 MB

    prep_kernel<<<481, 256, 0, stream>>>(Wih0, Whh0, Wih1, Whh1, Wfc, emb,
                                         w0b, u0b, w1b, u1b, wfcb, partials);
    xw_kernel<<<64 * 64, 512, 0, stream>>>(text, bih0, bhh0, emb, partials, w0b, T0p);
    scan_kernel<<<64, 512, 0, stream>>>(bih1, bhh1, u0b, w1b, u1b, wfcb, T0p, out);
}

// Round 10
// 394.336 us; speedup vs baseline: 1.7326x; 1.0114x over previous
//
#include <hip/hip_runtime.h>

typedef unsigned long long u64;

// Pass-through that makes the value asm-defined: the compiler cannot
// rematerialize the originating load inside the loop.
__device__ __forceinline__ u64 opaque64(u64 x) { asm volatile("" : "+v"(x)); return x; }

// Workgroup barrier that orders LDS only (no vmcnt drain), so global-memory
// prefetch loads stay in flight across it.
__device__ __forceinline__ void lds_barrier() {
    asm volatile("s_waitcnt lgkmcnt(0)" ::: "memory");
    __builtin_amdgcn_s_barrier();
    asm volatile("" ::: "memory");
}

// ---------------- prep: weight bit-pack (blocks 0..224) + amax partials (225..480) ----------------
__global__ void prep_kernel(const float* __restrict__ Wih0, const float* __restrict__ Whh0,
                            const float* __restrict__ Wih1, const float* __restrict__ Whh1,
                            const float* __restrict__ Wfc, const float* __restrict__ emb,
                            u64* __restrict__ w0b, u64* __restrict__ u0b,
                            u64* __restrict__ w1b, u64* __restrict__ u1b,
                            u64* __restrict__ wfcb, float* __restrict__ partials) {
    const int blk = blockIdx.x;
    const int lane = threadIdx.x & 63;
    if (blk < 225) {
        const int gw = (blk * 256 + threadIdx.x) >> 6;  // global wave id
        if (gw >= 897) return;
        const int wb = gw * 16;  // first packed word of this chunk
        const float* srcb; u64* dstb; int nw = 16;
        if (wb < 2048)       { srcb = Wih0 + (long long)wb * 64;           dstb = w0b + wb; }
        else if (wb < 6144)  { srcb = Whh0 + (long long)(wb - 2048) * 64;  dstb = u0b + (wb - 2048); }
        else if (wb < 10240) { srcb = Wih1 + (long long)(wb - 6144) * 64;  dstb = w1b + (wb - 6144); }
        else if (wb < 14336) { srcb = Whh1 + (long long)(wb - 10240) * 64; dstb = u1b + (wb - 10240); }
        else                 { srcb = Wfc  + (long long)(wb - 14336) * 64; dstb = wfcb + (wb - 14336); nw = 8; }
        u64 mine = 0;
        for (int k0 = 0; k0 < nw; k0 += 8) {
            float v[8];
#pragma unroll
            for (int j = 0; j < 8; ++j) v[j] = srcb[(long long)(k0 + j) * 64 + lane];
#pragma unroll
            for (int j = 0; j < 8; ++j) {
                u64 bits = __ballot(v[j] >= 0.0f);
                if (lane == k0 + j) mine = bits;
            }
        }
        if (lane < nw) dstb[lane] = mine;   // coalesced 8B stores
    } else {
        const int ab = blk - 225;           // 0..255
        const float4* e4 = (const float4*)emb + (long long)ab * 8000;
        float m = 0.0f;
        for (int i = threadIdx.x; i < 8000; i += 256) {
            float4 v = e4[i];
            m = fmaxf(m, fmaxf(fmaxf(fabsf(v.x), fabsf(v.y)), fmaxf(fabsf(v.z), fabsf(v.w))));
        }
#pragma unroll
        for (int off = 32; off > 0; off >>= 1) m = fmaxf(m, __shfl_down(m, off, 64));
        if (lane == 0) partials[ab * 4 + (threadIdx.x >> 6)] = m;  // 1024 partials
    }
}

// ---------------- layer-0 input-threshold precompute, 32 timesteps/block ----------------
// T0[b][t][h] = floor((512 + xw)/2), xw = fl(fl((256-2*mm0)+bih0)+bhh0).
// Exact: sign(fl(xw + (512-2*mh0))) >= 0  <=>  mh0 <= T0   (h=0 case: mh0:=256).
// Stored as i16 pairs: dword (b*256 + t/2)*512 + h holds {t even, t odd}.
// Block (b,tg) covers t = tg*32 .. tg*32+31; wave wv binarizes tokens wv*4..wv*4+3.
__global__ void xw_kernel(const int* __restrict__ text,
                          const float* __restrict__ bih0, const float* __restrict__ bhh0,
                          const float* __restrict__ emb, const float* __restrict__ partials,
                          const u64* __restrict__ w0b, int* __restrict__ T0p) {
    const int tid = threadIdx.x;
    const int lane = tid & 63;
    const int wv = tid >> 6;      // 0..7
    const int b = blockIdx.x >> 4;
    const int tg = blockIdx.x & 15;
    __shared__ __align__(16) u64 xbs[32][4];

    // amax reduce -> threshold: bit = rint(v/s)>=0 <=> v >= -s/2 (s = 2^e exact)
    float m = 0.0f;
#pragma unroll
    for (int j = 0; j < 16; ++j) m = fmaxf(m, partials[lane + 64 * j]);
#pragma unroll
    for (int off = 32; off > 0; off >>= 1) m = fmaxf(m, __shfl_xor(m, off));
    const float thr = -0.5f * exp2f(ceilf(log2f((m + 1e-12f) / 127.0f)));

    // wave wv binarizes rows of tokens t = tg*32 + wv*4 + j (coalesced 256B chunks)
#pragma unroll
    for (int j = 0; j < 4; ++j) {
        const int tl = wv * 4 + j;
        const int tok = text[b * 512 + tg * 32 + tl];
        const float* row = emb + (size_t)tok * 256;
        float v0 = row[lane], v1 = row[64 + lane], v2 = row[128 + lane], v3 = row[192 + lane];
        u64 q0 = __ballot(v0 >= thr);
        u64 q1 = __ballot(v1 >= thr);
        u64 q2 = __ballot(v2 >= thr);
        u64 q3 = __ballot(v3 >= thr);
        if (lane == 0) { xbs[tl][0] = q0; xbs[tl][1] = q1; xbs[tl][2] = q2; xbs[tl][3] = q3; }
    }
    u64 w0[4];
#pragma unroll
    for (int w = 0; w < 4; ++w) w0[w] = w0b[tid * 4 + w];
    const float bi = bih0[tid], bh = bhh0[tid];
    __syncthreads();

    int* outp = T0p + ((size_t)b * 256 + tg * 16) * 512 + tid;   // +512 per t-pair
    int lo = 0;
#pragma unroll
    for (int t8 = 0; t8 < 32; ++t8) {
        int mm = 0;
#pragma unroll
        for (int w = 0; w < 4; ++w) mm += __popcll(xbs[t8][w] ^ w0[w]);
        float xw = ((float)(256 - 2 * mm) + bi) + bh;
        int T0 = (int)floor((512.0 + (double)xw) * 0.5);   // exact (<= 41 mantissa bits)
        if ((t8 & 1) == 0) lo = T0;
        else {
            outp[(t8 >> 1) * 512] = (lo & 0xffff) | (T0 << 16);
        }
    }
}

// ---------------- sequential scan: layer-1 lagged one step; interleaved state ----------------
// 64 blocks (1/batch) x 512 threads (8 waves, 2/SIMD). Thread = one h unit of
// both layers; pinned weights u0,w1,u1 = 24 u64 = 48 VGPR (proven <= 88 cap).
// State: st[par][w] = {h0_word_w, h1_word_w}; phase p reads st[(p-1)&1],
// writes st[p&1] -- lane0 publishes BOTH ballots with one ds_write_b128.
// Layer-0 update is an integer threshold test vs the precomputed T0 stream
// (prefetched 2 pair-iterations ahead; vmcnt-immune to lds_barrier). The
// prefetch loop runs 253 iters (reaches exactly pair 255) + 2 peeled
// pair-iterations -> no pointer clamp in the steady state.
__global__ __attribute__((amdgpu_flat_work_group_size(512, 512), amdgpu_waves_per_eu(2, 2)))
void scan_kernel(const float* __restrict__ bih1, const float* __restrict__ bhh1,
                 const u64* __restrict__ u0b, const u64* __restrict__ w1b,
                 const u64* __restrict__ u1b, const u64* __restrict__ wfcb,
                 const int* __restrict__ T0d, float* __restrict__ out) {
    __shared__ __align__(16) ulonglong2 st[2][8];

    const int tid = threadIdx.x;
    const int b = blockIdx.x;
    const int lane = tid & 63;
    const int wv = tid >> 6;

    u64 u0[8], w1[8], u1[8];
#pragma unroll
    for (int w = 0; w < 8; ++w) u0[w] = opaque64(u0b[tid * 8 + w]);
#pragma unroll
    for (int w = 0; w < 8; ++w) w1[w] = opaque64(w1b[tid * 8 + w]);
#pragma unroll
    for (int w = 0; w < 8; ++w) u1[w] = opaque64(u1b[tid * 8 + w]);
    const float bi1 = bih1[tid], bh1 = bhh1[tid];

    const int* T0row = T0d + (size_t)b * (256 * 512) + tid;  // +512 per t-pair
    int pc = T0row[0];          // pair {t0,t1}   (consumed in phases 0,1)
    int pn = T0row[512];        // pair {t2,t3}
    int p2 = T0row[1024];       // pair {t4,t5}
    const int* Tptr = T0row + 1536;   // -> pair 3

    // ---- phase 0: h0[0] (h0[-1]=0 -> condition 256 <= T0(t0)); h1 word junk ----
    {
        u64 b0 = __ballot(256 <= (int)(short)(pc & 0xffff));
        if (lane == 0) { ulonglong2 v; v.x = b0; v.y = 0; st[0][wv] = v; }
        lds_barrier();
    }
    // ---- phase 1: h0[1] (T0(t1)); h1[0] with forced HU=0 (reads .x only) ----
    {
        ulonglong2 s0 = st[0][0], s1 = st[0][1], s2 = st[0][2], s3 = st[0][3],
                   s4 = st[0][4], s5 = st[0][5], s6 = st[0][6], s7 = st[0][7];
        int mh0 = __popcll(s0.x ^ u0[0]) + __popcll(s1.x ^ u0[1]) + __popcll(s2.x ^ u0[2])
                + __popcll(s3.x ^ u0[3]) + __popcll(s4.x ^ u0[4]) + __popcll(s5.x ^ u0[5])
                + __popcll(s6.x ^ u0[6]) + __popcll(s7.x ^ u0[7]);
        int mx1 = __popcll(s0.x ^ w1[0]) + __popcll(s1.x ^ w1[1]) + __popcll(s2.x ^ w1[2])
                + __popcll(s3.x ^ w1[3]) + __popcll(s4.x ^ w1[4]) + __popcll(s5.x ^ w1[5])
                + __popcll(s6.x ^ w1[6]) + __popcll(s7.x ^ w1[7]);
        u64 b0 = __ballot(mh0 <= (int)(short)(pc >> 16));
        float c1 = ((float)(512 - 2 * mx1) + bi1) + bh1;
        u64 b1 = __ballot(c1 >= 0.0f);
        if (lane == 0) { ulonglong2 v; v.x = b0; v.y = b1; st[1][wv] = v; }
        lds_barrier();
    }

    // PHASE: h0 threshold test + h1 float chain, exact JAX association (R5-verified):
    // h0: mh0 <= T0; h1: fl(c1+(512-2mh1))>=0 <=> c1 >= (float)(2mh1-512).
#define PHASE(RD, WR, T0IMM)                                                        \
    {                                                                               \
        ulonglong2 s0 = st[RD][0], s1 = st[RD][1], s2 = st[RD][2], s3 = st[RD][3],  \
                   s4 = st[RD][4], s5 = st[RD][5], s6 = st[RD][6], s7 = st[RD][7];  \
        int mh0 = __popcll(s0.x ^ u0[0]) + __popcll(s1.x ^ u0[1])                   \
                + __popcll(s2.x ^ u0[2]) + __popcll(s3.x ^ u0[3])                   \
                + __popcll(s4.x ^ u0[4]) + __popcll(s5.x ^ u0[5])                   \
                + __popcll(s6.x ^ u0[6]) + __popcll(s7.x ^ u0[7]);                  \
        int mx1 = __popcll(s0.x ^ w1[0]) + __popcll(s1.x ^ w1[1])                   \
                + __popcll(s2.x ^ w1[2]) + __popcll(s3.x ^ w1[3])                   \
                + __popcll(s4.x ^ w1[4]) + __popcll(s5.x ^ w1[5])                   \
                + __popcll(s6.x ^ w1[6]) + __popcll(s7.x ^ w1[7]);                  \
        int mh1 = __popcll(s0.y ^ u1[0]) + __popcll(s1.y ^ u1[1])                   \
                + __popcll(s2.y ^ u1[2]) + __popcll(s3.y ^ u1[3])                   \
                + __popcll(s4.y ^ u1[4]) + __popcll(s5.y ^ u1[5])                   \
                + __popcll(s6.y ^ u1[6]) + __popcll(s7.y ^ u1[7]);                  \
        u64 b0 = __ballot(mh0 <= (int)(T0IMM));                                     \
        float c1 = ((float)(512 - 2 * mx1) + bi1) + bh1;                            \
        u64 b1 = __ballot(c1 >= (float)(2 * mh1 - 512));                            \
        if (lane == 0) { ulonglong2 v; v.x = b0; v.y = b1; st[WR][wv] = v; }        \
        lds_barrier();                                                              \
    }

    // main loop: phases p (even: rd=1,wr=0) and p+1 (odd: rd=0,wr=1).
    // Iteration p consumes pair p/2 (in pn) and prefetches pair p/2+2; the last
    // prefetch (p=506) reads pair 255 -- never out of bounds.
    for (int p = 2; p < 508; p += 2) {
        int pf = *Tptr; Tptr += 512;
        PHASE(1, 0, (short)(pn & 0xffff));
        PHASE(0, 1, (short)(pn >> 16));
        pn = p2; p2 = pf;
    }
    // phases 508,509 (pair 254) and 510,511 (pair 255), no prefetch
    PHASE(1, 0, (short)(pn & 0xffff));
    PHASE(0, 1, (short)(pn >> 16));
    pn = p2;
    PHASE(1, 0, (short)(pn & 0xffff));
    PHASE(0, 1, (short)(pn >> 16));
    // phase 512: h1[511] only; h0 part junk (overwrites dead h0[510] in st[0]);
    // reads h0[511], h1[510] from st[1].
    PHASE(1, 0, 0);
#undef PHASE

    // fused final dense: out[layer*64 + b] = hT . sign(Wfc)
    if (tid < 2) {
        int mm = 0;
#pragma unroll
        for (int w = 0; w < 8; ++w) {
            u64 hw = (tid == 0) ? st[1][w].x : st[0][w].y;  // h0[511] / h1[511]
            mm += __popcll(hw ^ wfcb[w]);
        }
        out[tid * 64 + b] = (float)(512 - 2 * mm);
    }
}

extern "C" void kernel_launch(void* const* d_in, const int* in_sizes, int n_in,
                              void* d_out, int out_size, void* d_ws, size_t ws_size,
                              hipStream_t stream) {
    const int* text = (const int*)d_in[0];
    // d_in[1] = text_lengths : unused by the reference computation
    const float* emb = (const float*)d_in[2];
    const float* Wih0 = (const float*)d_in[3];
    const float* Whh0 = (const float*)d_in[4];
    const float* bih0 = (const float*)d_in[5];
    const float* bhh0 = (const float*)d_in[6];
    const float* Wih1 = (const float*)d_in[7];
    const float* Whh1 = (const float*)d_in[8];
    const float* bih1 = (const float*)d_in[9];
    const float* bhh1 = (const float*)d_in[10];
    const float* Wfc = (const float*)d_in[11];
    float* out = (float*)d_out;

    // workspace layout (u64 units)
    u64* ws = (u64*)d_ws;
    u64* w0b = ws;                  // 512*4 = 2048
    u64* u0b = w0b + 2048;          // 4096
    u64* w1b = u0b + 4096;          // 4096
    u64* u1b = w1b + 4096;          // 4096
    u64* wfcb = u1b + 4096;         // 8
    float* partials = (float*)(wfcb + 8);    // 1024 floats = 512 u64
    int* T0p = (int*)(partials + 1024);      // 64*256*512 dwords = 32 MB

    prep_kernel<<<481, 256, 0, stream>>>(Wih0, Whh0, Wih1, Whh1, Wfc, emb,
                                         w0b, u0b, w1b, u1b, wfcb, partials);
    xw_kernel<<<64 * 16, 512, 0, stream>>>(text, bih0, bhh0, emb, partials, w0b, T0p);
    scan_kernel<<<64, 512, 0, stream>>>(bih1, bhh1, u0b, w1b, u1b, wfcb, T0p, out);
}